// Round 1
// baseline (2793.017 us; speedup 1.0000x reference)
//
#include <hip/hip_runtime.h>

#define NB 64   // batch
#define CS 64   // states
#define LL 8192 // sequence length

// One wave (64 lanes) per batch element. Lane j owns state j:
//   - E[i] = exp(T[i][j])  (column j of transition matrix) in registers
//   - q[j] = exp(alpha[j] - ln2*carry), renormalized by exact powers of two
// Per step: broadcast q via LDS, s[j] = sum_i q[i]*E[i], q = s * exp(em[t][j]).
__global__ __launch_bounds__(64, 1)
void crf_scan(const float* __restrict__ obs, const float* __restrict__ trans,
              float* __restrict__ out) {
    const int n = blockIdx.x;
    const int j = threadIdx.x;
    __shared__ __align__(16) float qbuf[CS];

    // Load E column j (exp of transitions). 16 KB matrix -> L2; once.
    float E[CS];
#pragma unroll
    for (int i = 0; i < CS; ++i) E[i] = __expf(trans[i * CS + j]);

    const float* __restrict__ row = obs + ((size_t)n * CS + j) * (size_t)LL;

    // chunk 0 preload (8 timesteps per chunk)
    float4 a0 = *(const float4*)(row + 0);
    float4 a1 = *(const float4*)(row + 4);

    float q = __expf(a0.x);   // alpha0 = em[0]; q = exp(alpha0), carry = 0
    int carry = 0;

#pragma unroll 1
    for (int c = 0; c < LL / 8; ++c) {
        // prefetch next chunk (clamped; last iteration re-reads harmlessly)
        const int cn = (c + 1 < LL / 8) ? c + 1 : (LL / 8 - 1);
        float4 b0 = *(const float4*)(row + 8 * cn + 0);
        float4 b1 = *(const float4*)(row + 8 * cn + 4);

        // exp(em) for this chunk — off the critical path
        float ee[8];
        ee[0] = __expf(a0.x); ee[1] = __expf(a0.y);
        ee[2] = __expf(a0.z); ee[3] = __expf(a0.w);
        ee[4] = __expf(a1.x); ee[5] = __expf(a1.y);
        ee[6] = __expf(a1.z); ee[7] = __expf(a1.w);

#pragma unroll
        for (int k = 0; k < 8; ++k) {
            if (c == 0 && k == 0) continue;   // t=0 consumed by init

            // --- one recurrence step ---
            qbuf[j] = q;
            asm volatile("s_waitcnt lgkmcnt(0)" ::: "memory");
            const float4* qb4 = (const float4*)qbuf;  // broadcast reads
            float2 s0 = {0.f, 0.f}, s1 = {0.f, 0.f};
            float2 s2 = {0.f, 0.f}, s3 = {0.f, 0.f};
#pragma unroll
            for (int m = 0; m < 16; m += 2) {
                float4 qa = qb4[m];
                s0.x = fmaf(qa.x, E[4 * m + 0], s0.x);
                s0.y = fmaf(qa.y, E[4 * m + 1], s0.y);
                s1.x = fmaf(qa.z, E[4 * m + 2], s1.x);
                s1.y = fmaf(qa.w, E[4 * m + 3], s1.y);
                float4 qc = qb4[m + 1];
                s2.x = fmaf(qc.x, E[4 * m + 4], s2.x);
                s2.y = fmaf(qc.y, E[4 * m + 5], s2.y);
                s3.x = fmaf(qc.z, E[4 * m + 6], s3.x);
                s3.y = fmaf(qc.w, E[4 * m + 7], s3.y);
            }
            float s = ((s0.x + s0.y) + (s1.x + s1.y)) +
                      ((s2.x + s2.y) + (s3.x + s3.y));
            q = s * ee[k];

            // exact power-of-two renorm every 4 steps (lane-0 proxy; cheap,
            // no cross-lane reduce; fp32 range analysis gives huge margin)
            if ((k & 3) == 3) {
                unsigned qb0 = (unsigned)__builtin_amdgcn_readfirstlane(
                    (int)__float_as_uint(q));
                int e = (int)((qb0 >> 23) & 0xffu) - 126;
                q = ldexpf(q, -e);
                carry += e;
            }
        }
        a0 = b0; a1 = b1;
    }

    // log_Z = ln2*carry + log(sum_j q[j])
    float s = q;
#pragma unroll
    for (int off = 32; off > 0; off >>= 1) s += __shfl_xor(s, off, 64);
    if (j == 0) {
        float logZ = (float)carry * 0.6931471805599453f + __logf(s);
        atomicAdd(out, logZ * (1.0f / NB));
    }
}

// gold_em[n] + gold_tr[n], subtracted from the output.
__global__ __launch_bounds__(256)
void crf_gold(const float* __restrict__ obs, const float* __restrict__ trans,
              const int* __restrict__ tgt, float* __restrict__ out) {
    const int n = blockIdx.x;
    const int tid = threadIdx.x;
    const int* __restrict__ trow = tgt + (size_t)n * LL;
    float acc = 0.f;
    for (int t = tid; t < LL; t += 256) {
        int s = trow[t];
        acc += obs[((size_t)n * CS + s) * (size_t)LL + t];
        if (t + 1 < LL) acc += trans[s * CS + trow[t + 1]];
    }
#pragma unroll
    for (int off = 32; off > 0; off >>= 1) acc += __shfl_xor(acc, off, 64);
    __shared__ float red[4];
    if ((tid & 63) == 0) red[tid >> 6] = acc;
    __syncthreads();
    if (tid == 0) {
        float tot = red[0] + red[1] + red[2] + red[3];
        atomicAdd(out, -tot * (1.0f / NB));
    }
}

extern "C" void kernel_launch(void* const* d_in, const int* in_sizes, int n_in,
                              void* d_out, int out_size, void* d_ws, size_t ws_size,
                              hipStream_t stream) {
    const float* obs   = (const float*)d_in[0];
    const float* trans = (const float*)d_in[1];
    const int*   tgt   = (const int*)d_in[2];
    float* out = (float*)d_out;

    hipMemsetAsync(out, 0, sizeof(float), stream);
    crf_gold<<<NB, 256, 0, stream>>>(obs, trans, tgt, out);
    crf_scan<<<NB, 64, 0, stream>>>(obs, trans, out);
}

// Round 2
// 1663.748 us; speedup vs baseline: 1.6788x; 1.6788x over previous
//
#include <hip/hip_runtime.h>

#define NB 64   // batch
#define CS 64   // states
#define LL 8192 // sequence length

#ifndef __has_builtin
#define __has_builtin(x) 0
#endif

__device__ __forceinline__ float uif(unsigned int u) { return __uint_as_float(u); }
__device__ __forceinline__ unsigned int fiu(float f) { return __float_as_uint(f); }

// DPP-fused FMA: acc += row_ror(q) * E   (rotation on src0 comes free)
#define FMAC_DPP(ACC, Q, EV, R)                                                 \
  asm volatile("v_fmac_f32_dpp %0, %1, %2 row_ror:" #R                          \
               " row_mask:0xf bank_mask:0xf"                                    \
               : "+v"(ACC) : "v"(Q), "v"(EV))

#define ROW4(R)                                                                 \
  FMAC_DPP(acc0, qr0, Em[0][R], R);                                             \
  FMAC_DPP(acc1, qr1, Em[1][R], R);                                             \
  FMAC_DPP(acc2, qr2, Em[2][R], R);                                             \
  FMAC_DPP(acc3, qr3, Em[3][R], R)

// One wave per batch element. Lane j owns state j. Zero LDS on the critical
// path: q-row replication via permlane swaps, all-to-all via DPP row_ror.
__global__ __launch_bounds__(64, 1)
void crf_scan(const float* __restrict__ obs, const float* __restrict__ trans,
              float* __restrict__ out) {
  const int n = blockIdx.x;
  const int j = threadIdx.x;

  // --- one-off DPP direction calibration (wave-uniform) ---
  // row_ror:1 probe on lane index: lane1 sees 0 if dst[i]=src[(i-1)&15], else 2.
  int w = __builtin_amdgcn_update_dpp(0, j, 0x121 /*row_ror:1*/, 0xf, 0xf, true);
  const int dsel = __builtin_amdgcn_readlane(w, 1);

  // E_perm[g][r] at lane j = exp(T[i][j]), i = 16g + ((j -/+ r) & 15)
  float Em[4][16];
#pragma unroll
  for (int g = 0; g < 4; ++g) {
#pragma unroll
    for (int r = 0; r < 16; ++r) {
      int irm = (j - r) & 15;
      int irp = (j + r) & 15;
      int ir = (dsel == 0) ? irm : irp;
      Em[g][r] = __expf(trans[(16 * g + ir) * CS + j]);
    }
  }

  const float* __restrict__ row = obs + ((size_t)n * CS + j) * (size_t)LL;
  float4 a0 = *(const float4*)(row);
  float4 a1 = *(const float4*)(row + 4);

  float q = __expf(a0.x);  // alpha0 = em[0]
  int carry = 0;

#pragma unroll 1
  for (int c = 0; c < LL / 8; ++c) {
    const int cn = (c + 1 < LL / 8) ? c + 1 : (LL / 8 - 1);
    float4 b0 = *(const float4*)(row + 8 * cn);
    float4 b1 = *(const float4*)(row + 8 * cn + 4);

    float ee[8];
    ee[0] = __expf(a0.x); ee[1] = __expf(a0.y);
    ee[2] = __expf(a0.z); ee[3] = __expf(a0.w);
    ee[4] = __expf(a1.x); ee[5] = __expf(a1.y);
    ee[6] = __expf(a1.z); ee[7] = __expf(a1.w);

#pragma unroll
    for (int k = 0; k < 8; ++k) {
      if (c == 0 && k == 0) continue;  // t=0 consumed by init

      // replicate q row-groups to all lanes: qr_g[j] = q[16g + (j&15)]
#if __has_builtin(__builtin_amdgcn_permlane16_swap) && \
    __has_builtin(__builtin_amdgcn_permlane32_swap)
      unsigned qb = fiu(q);
      auto h = __builtin_amdgcn_permlane16_swap(qb, qb, false, false);
      // h[0]=[r0,r0,r2,r2], h[1]=[r1,r1,r3,r3] (16-lane row units)
      auto A = __builtin_amdgcn_permlane32_swap(h[0], h[0], false, false);
      auto B = __builtin_amdgcn_permlane32_swap(h[1], h[1], false, false);
      float qr0 = uif(A[0]), qr2 = uif(A[1]);
      float qr1 = uif(B[0]), qr3 = uif(B[1]);
#else
      float qr0 = __shfl(q,  0 + (j & 15), 64);
      float qr1 = __shfl(q, 16 + (j & 15), 64);
      float qr2 = __shfl(q, 32 + (j & 15), 64);
      float qr3 = __shfl(q, 48 + (j & 15), 64);
#endif

      float acc0 = qr0 * Em[0][0];
      float acc1 = qr1 * Em[1][0];
      float acc2 = qr2 * Em[2][0];
      float acc3 = qr3 * Em[3][0];
      asm volatile("s_nop 1" :::);  // VALU-write -> DPP-read hazard guard
      ROW4(1);  ROW4(2);  ROW4(3);  ROW4(4);  ROW4(5);
      ROW4(6);  ROW4(7);  ROW4(8);  ROW4(9);  ROW4(10);
      ROW4(11); ROW4(12); ROW4(13); ROW4(14); ROW4(15);
      float s = (acc0 + acc1) + (acc2 + acc3);
      q = s * ee[k];

      // exact power-of-two renorm every 4 steps (lane-0 exponent proxy)
      if ((k & 3) == 3) {
        unsigned q0 = (unsigned)__builtin_amdgcn_readfirstlane((int)fiu(q));
        int e = (int)((q0 >> 23) & 0xffu) - 126;
        q = ldexpf(q, -e);
        carry += e;
      }
    }
    a0 = b0; a1 = b1;
  }

  // log_Z = ln2*carry + log(sum_j q[j])
  float s = q;
#pragma unroll
  for (int off = 32; off > 0; off >>= 1) s += __shfl_xor(s, off, 64);
  if (j == 0) {
    float logZ = (float)carry * 0.6931471805599453f + __logf(s);
    atomicAdd(out, logZ * (1.0f / NB));
  }
}

// gold_em[n] + gold_tr[n], subtracted from the output.
__global__ __launch_bounds__(256)
void crf_gold(const float* __restrict__ obs, const float* __restrict__ trans,
              const int* __restrict__ tgt, float* __restrict__ out) {
  const int n = blockIdx.x;
  const int tid = threadIdx.x;
  const int* __restrict__ trow = tgt + (size_t)n * LL;
  float acc = 0.f;
  for (int t = tid; t < LL; t += 256) {
    int s = trow[t];
    acc += obs[((size_t)n * CS + s) * (size_t)LL + t];
    if (t + 1 < LL) acc += trans[s * CS + trow[t + 1]];
  }
#pragma unroll
  for (int off = 32; off > 0; off >>= 1) acc += __shfl_xor(acc, off, 64);
  __shared__ float red[4];
  if ((tid & 63) == 0) red[tid >> 6] = acc;
  __syncthreads();
  if (tid == 0) {
    float tot = red[0] + red[1] + red[2] + red[3];
    atomicAdd(out, -tot * (1.0f / NB));
  }
}

extern "C" void kernel_launch(void* const* d_in, const int* in_sizes, int n_in,
                              void* d_out, int out_size, void* d_ws, size_t ws_size,
                              hipStream_t stream) {
  const float* obs   = (const float*)d_in[0];
  const float* trans = (const float*)d_in[1];
  const int*   tgt   = (const int*)d_in[2];
  float* out = (float*)d_out;

  hipMemsetAsync(out, 0, sizeof(float), stream);
  crf_gold<<<NB, 256, 0, stream>>>(obs, trans, tgt, out);
  crf_scan<<<NB, 64, 0, stream>>>(obs, trans, out);
}

// Round 3
// 1660.208 us; speedup vs baseline: 1.6823x; 1.0021x over previous
//
#include <hip/hip_runtime.h>

#define NB 64   // batch
#define CS 64   // states
#define LL 8192 // sequence length

__device__ __forceinline__ float uif(unsigned int u) { return __uint_as_float(u); }
__device__ __forceinline__ unsigned int fiu(float f) { return __float_as_uint(f); }

// DPP-fused MAC: acc += row_ror(q) * E   (rotation on src0 comes free)
#define FMAC_DPP(ACC, Q, EV, R)                                                 \
  asm volatile("v_fmac_f32_dpp %0, %1, %2 row_ror:" #R                          \
               " row_mask:0xf bank_mask:0xf"                                    \
               : "+v"(ACC) : "v"(Q), "v"(EV))
// DPP mul (accumulator-chain start, no zero-init needed)
#define MUL_DPP(DST, Q, EV, R)                                                  \
  asm volatile("v_mul_f32_dpp %0, %1, %2 row_ror:" #R                           \
               " row_mask:0xf bank_mask:0xf"                                    \
               : "=v"(DST) : "v"(Q), "v"(EV))

// 8 FMACs: even rotation RE into accA0..3, odd RO into accB0..3.
// Dependent reuse of any acc register is 8 instructions (16 cycles) apart.
#define ROWPAIR(RE, RO)                                                         \
  FMAC_DPP(accA0, qr0, Em[0][RE], RE);                                          \
  FMAC_DPP(accA1, qr1, Em[1][RE], RE);                                          \
  FMAC_DPP(accA2, qr2, Em[2][RE], RE);                                          \
  FMAC_DPP(accA3, qr3, Em[3][RE], RE);                                          \
  FMAC_DPP(accB0, qr0, Em[0][RO], RO);                                          \
  FMAC_DPP(accB1, qr1, Em[1][RO], RO);                                          \
  FMAC_DPP(accB2, qr2, Em[2][RO], RO);                                          \
  FMAC_DPP(accB3, qr3, Em[3][RO], RO)

// One wave per batch element. Lane j owns state j. Zero LDS on the critical
// path: q-row replication via permlane swaps, all-to-all via DPP row_ror.
__global__ __launch_bounds__(64, 1)
void crf_scan(const float* __restrict__ obs, const float* __restrict__ trans,
              float* __restrict__ out) {
  const int n = blockIdx.x;
  const int j = threadIdx.x;

  // one-off DPP direction calibration (wave-uniform)
  int w = __builtin_amdgcn_update_dpp(0, j, 0x121 /*row_ror:1*/, 0xf, 0xf, true);
  const int dsel = __builtin_amdgcn_readlane(w, 1);

  // E_perm[g][r] at lane j = exp(T[i][j]), i = 16g + ((j -/+ r) & 15)
  float Em[4][16];
#pragma unroll
  for (int g = 0; g < 4; ++g) {
#pragma unroll
    for (int r = 0; r < 16; ++r) {
      int irm = (j - r) & 15;
      int irp = (j + r) & 15;
      int ir = (dsel == 0) ? irm : irp;
      Em[g][r] = __expf(trans[(16 * g + ir) * CS + j]);
    }
  }

  const float* __restrict__ row = obs + ((size_t)n * CS + j) * (size_t)LL;
  float4 a0 = *(const float4*)(row);
  float4 a1 = *(const float4*)(row + 4);

  float q = __expf(a0.x);  // alpha0 = em[0]
  int carry = 0;

#pragma unroll 1
  for (int c = 0; c < LL / 8; ++c) {
    const int cn = (c + 1 < LL / 8) ? c + 1 : (LL / 8 - 1);
    float4 b0 = *(const float4*)(row + 8 * cn);
    float4 b1 = *(const float4*)(row + 8 * cn + 4);

    float ee[8];
    ee[0] = __expf(a0.x); ee[1] = __expf(a0.y);
    ee[2] = __expf(a0.z); ee[3] = __expf(a0.w);
    ee[4] = __expf(a1.x); ee[5] = __expf(a1.y);
    ee[6] = __expf(a1.z); ee[7] = __expf(a1.w);

#pragma unroll
    for (int k = 0; k < 8; ++k) {
      if (c == 0 && k == 0) continue;  // t=0 consumed by init

      // replicate q row-groups to all lanes: qr_g[j] = q[16g + (j&15)]
      unsigned qb = fiu(q);
      auto h = __builtin_amdgcn_permlane16_swap(qb, qb, false, false);
      auto A = __builtin_amdgcn_permlane32_swap(h[0], h[0], false, false);
      auto B = __builtin_amdgcn_permlane32_swap(h[1], h[1], false, false);
      float qr0 = uif(A[0]), qr2 = uif(A[1]);
      float qr1 = uif(B[0]), qr3 = uif(B[1]);

      // r=0 chain starts (plain muls, also provide compiler-visible qr uses)
      float accA0 = qr0 * Em[0][0];
      float accA1 = qr1 * Em[1][0];
      float accA2 = qr2 * Em[2][0];
      float accA3 = qr3 * Em[3][0];
      float accB0, accB1, accB2, accB3;
      asm volatile("s_nop 1" :::);  // VALU-write -> DPP-read hazard guard
      // r=1 chain starts via DPP muls
      MUL_DPP(accB0, qr0, Em[0][1], 1);
      MUL_DPP(accB1, qr1, Em[1][1], 1);
      MUL_DPP(accB2, qr2, Em[2][1], 1);
      MUL_DPP(accB3, qr3, Em[3][1], 1);
      ROWPAIR(2, 3);   ROWPAIR(4, 5);   ROWPAIR(6, 7);
      ROWPAIR(8, 9);   ROWPAIR(10, 11); ROWPAIR(12, 13);
      ROWPAIR(14, 15);
      float s = ((accA0 + accB0) + (accA1 + accB1)) +
                ((accA2 + accB2) + (accA3 + accB3));
      q = s * ee[k];

      // exact power-of-two renorm every 4 steps (lane-0 exponent proxy),
      // branchless: subtract e from the exponent field directly.
      if ((k & 3) == 3) {
        int q0 = __builtin_amdgcn_readfirstlane((int)fiu(q));
        int e = ((q0 >> 23) & 0xff) - 126;
        carry += e;
        q = uif(fiu(q) - (unsigned)(e << 23));
      }
    }
    a0 = b0; a1 = b1;
  }

  // log_Z = ln2*carry + log(sum_j q[j])
  float s = q;
#pragma unroll
  for (int off = 32; off > 0; off >>= 1) s += __shfl_xor(s, off, 64);
  if (j == 0) {
    float logZ = (float)carry * 0.6931471805599453f + __logf(s);
    atomicAdd(out, logZ * (1.0f / NB));
  }
}

// gold_em[n] + gold_tr[n], subtracted from the output.
__global__ __launch_bounds__(256)
void crf_gold(const float* __restrict__ obs, const float* __restrict__ trans,
              const int* __restrict__ tgt, float* __restrict__ out) {
  const int n = blockIdx.x;
  const int tid = threadIdx.x;
  const int* __restrict__ trow = tgt + (size_t)n * LL;
  float acc = 0.f;
  for (int t = tid; t < LL; t += 256) {
    int s = trow[t];
    acc += obs[((size_t)n * CS + s) * (size_t)LL + t];
    if (t + 1 < LL) acc += trans[s * CS + trow[t + 1]];
  }
#pragma unroll
  for (int off = 32; off > 0; off >>= 1) acc += __shfl_xor(acc, off, 64);
  __shared__ float red[4];
  if ((tid & 63) == 0) red[tid >> 6] = acc;
  __syncthreads();
  if (tid == 0) {
    float tot = red[0] + red[1] + red[2] + red[3];
    atomicAdd(out, -tot * (1.0f / NB));
  }
}

extern "C" void kernel_launch(void* const* d_in, const int* in_sizes, int n_in,
                              void* d_out, int out_size, void* d_ws, size_t ws_size,
                              hipStream_t stream) {
  const float* obs   = (const float*)d_in[0];
  const float* trans = (const float*)d_in[1];
  const int*   tgt   = (const int*)d_in[2];
  float* out = (float*)d_out;

  hipMemsetAsync(out, 0, sizeof(float), stream);
  crf_gold<<<NB, 256, 0, stream>>>(obs, trans, tgt, out);
  crf_scan<<<NB, 64, 0, stream>>>(obs, trans, out);
}

// Round 4
// 1603.434 us; speedup vs baseline: 1.7419x; 1.0354x over previous
//
#include <hip/hip_runtime.h>

#define NB 64   // batch
#define CS 64   // states
#define LL 8192 // sequence length

__device__ __forceinline__ float uif(unsigned int u) { return __uint_as_float(u); }
__device__ __forceinline__ unsigned int fiu(float f) { return __float_as_uint(f); }

// 64 individually-named E registers: Em_g_r  (g=0..3 group, r=0..15 rotation).
// An array here spills to scratch (R2/R3: VGPR_Count=48 < 64 live values ->
// every MAC did a scratch load). Named scalars force register residency.
#define E_(G, R) Em_##G##_##R

#define DECL_E16(G)                                                             \
  float E_(G, 0), E_(G, 1), E_(G, 2), E_(G, 3), E_(G, 4), E_(G, 5), E_(G, 6),   \
      E_(G, 7), E_(G, 8), E_(G, 9), E_(G, 10), E_(G, 11), E_(G, 12),            \
      E_(G, 13), E_(G, 14), E_(G, 15)

#define INIT_E(G, R)                                                            \
  E_(G, R) = __expf(trans[(16 * G +                                             \
                           ((dsel == 0) ? ((j - R) & 15) : ((j + R) & 15))) *   \
                              CS +                                              \
                          j])

#define INIT_E16(G)                                                             \
  INIT_E(G, 0);  INIT_E(G, 1);  INIT_E(G, 2);  INIT_E(G, 3);                    \
  INIT_E(G, 4);  INIT_E(G, 5);  INIT_E(G, 6);  INIT_E(G, 7);                    \
  INIT_E(G, 8);  INIT_E(G, 9);  INIT_E(G, 10); INIT_E(G, 11);                   \
  INIT_E(G, 12); INIT_E(G, 13); INIT_E(G, 14); INIT_E(G, 15)

// DPP-fused MAC: acc += row_ror(q) * E   (rotation on src0 comes free)
#define FMAC_DPP(ACC, Q, G, R)                                                  \
  asm volatile("v_fmac_f32_dpp %0, %1, %2 row_ror:" #R                          \
               " row_mask:0xf bank_mask:0xf"                                    \
               : "+v"(ACC) : "v"(Q), "v"(E_(G, R)))

#define ROW4(R)                                                                 \
  FMAC_DPP(acc0, qr0, 0, R);                                                    \
  FMAC_DPP(acc1, qr1, 1, R);                                                    \
  FMAC_DPP(acc2, qr2, 2, R);                                                    \
  FMAC_DPP(acc3, qr3, 3, R)

__device__ __forceinline__ void crf_scan_block(const float* __restrict__ obs,
                                               const float* __restrict__ trans,
                                               float* __restrict__ out,
                                               int n, int j) {
  // one-off DPP direction calibration (wave-uniform)
  int w = __builtin_amdgcn_update_dpp(0, j, 0x121 /*row_ror:1*/, 0xf, 0xf, true);
  const int dsel = __builtin_amdgcn_readlane(w, 1);

  DECL_E16(0); DECL_E16(1); DECL_E16(2); DECL_E16(3);
  INIT_E16(0); INIT_E16(1); INIT_E16(2); INIT_E16(3);

  const float* __restrict__ row = obs + ((size_t)n * CS + j) * (size_t)LL;
  float4 a0 = *(const float4*)(row);
  float4 a1 = *(const float4*)(row + 4);

  float q = __expf(a0.x);  // alpha0 = em[0]
  int carry = 0;

#pragma unroll 1
  for (int c = 0; c < LL / 8; ++c) {
    const int cn = (c + 1 < LL / 8) ? c + 1 : (LL / 8 - 1);
    float4 b0 = *(const float4*)(row + 8 * cn);
    float4 b1 = *(const float4*)(row + 8 * cn + 4);

    float e0 = __expf(a0.x), e1 = __expf(a0.y), e2 = __expf(a0.z),
          e3 = __expf(a0.w), e4 = __expf(a1.x), e5 = __expf(a1.y),
          e6 = __expf(a1.z), e7 = __expf(a1.w);

#pragma unroll
    for (int k = 0; k < 8; ++k) {
      if (c == 0 && k == 0) continue;  // t=0 consumed by init

      // replicate q row-groups to all lanes: qr_g[j] = q[16g + (j&15)]
      unsigned qb = fiu(q);
      auto h = __builtin_amdgcn_permlane16_swap(qb, qb, false, false);
      auto A = __builtin_amdgcn_permlane32_swap(h[0], h[0], false, false);
      auto B = __builtin_amdgcn_permlane32_swap(h[1], h[1], false, false);
      float qr0 = uif(A[0]), qr2 = uif(A[1]);
      float qr1 = uif(B[0]), qr3 = uif(B[1]);

      // r=0 chain starts (plain muls)
      float acc0 = qr0 * E_(0, 0);
      float acc1 = qr1 * E_(1, 0);
      float acc2 = qr2 * E_(2, 0);
      float acc3 = qr3 * E_(3, 0);
      asm volatile("s_nop 1" :::);  // VALU-write -> DPP-read hazard guard
      ROW4(1);  ROW4(2);  ROW4(3);  ROW4(4);  ROW4(5);
      ROW4(6);  ROW4(7);  ROW4(8);  ROW4(9);  ROW4(10);
      ROW4(11); ROW4(12); ROW4(13); ROW4(14); ROW4(15);
      float s = (acc0 + acc1) + (acc2 + acc3);
      float ee = (k == 0) ? e0 : (k == 1) ? e1 : (k == 2) ? e2 : (k == 3) ? e3
               : (k == 4) ? e4 : (k == 5) ? e5 : (k == 6) ? e6 : e7;
      q = s * ee;

      // exact power-of-two renorm every 4 steps (lane-0 exponent proxy)
      if ((k & 3) == 3) {
        int q0 = __builtin_amdgcn_readfirstlane((int)fiu(q));
        int e = ((q0 >> 23) & 0xff) - 126;
        carry += e;
        q = uif(fiu(q) - (unsigned)(e << 23));
      }
    }
    a0 = b0; a1 = b1;
  }

  // log_Z = ln2*carry + log(sum_j q[j])
  float s = q;
#pragma unroll
  for (int off = 32; off > 0; off >>= 1) s += __shfl_xor(s, off, 64);
  if (j == 0) {
    float logZ = (float)carry * 0.6931471805599453f + __logf(s);
    atomicAdd(out, logZ * (1.0f / NB));
  }
}

__device__ __forceinline__ void crf_gold_block(const float* __restrict__ obs,
                                               const float* __restrict__ trans,
                                               const int* __restrict__ tgt,
                                               float* __restrict__ out, int n) {
  const int tid = threadIdx.x;
  const int* __restrict__ trow = tgt + (size_t)n * LL;
  float acc = 0.f;
  for (int t = tid; t < LL; t += 256) {
    int s = trow[t];
    acc += obs[((size_t)n * CS + s) * (size_t)LL + t];
    if (t + 1 < LL) acc += trans[s * CS + trow[t + 1]];
  }
#pragma unroll
  for (int off = 32; off > 0; off >>= 1) acc += __shfl_xor(acc, off, 64);
  __shared__ float red[4];
  if ((tid & 63) == 0) red[tid >> 6] = acc;
  __syncthreads();
  if (tid == 0) {
    float tot = red[0] + red[1] + red[2] + red[3];
    atomicAdd(out, -tot * (1.0f / NB));
  }
}

// Fused: blocks [0,64) run the scan (threads 0-63), blocks [64,128) run the
// gold gather-reduce — they execute concurrently on different CUs instead of
// serializing on the stream.
__global__ __launch_bounds__(256, 1)
void crf_fused(const float* __restrict__ obs, const float* __restrict__ trans,
               const int* __restrict__ tgt, float* __restrict__ out) {
  const int b = blockIdx.x;
  if (b < NB) {
    if (threadIdx.x < 64)
      crf_scan_block(obs, trans, out, b, threadIdx.x);
  } else {
    crf_gold_block(obs, trans, tgt, out, b - NB);
  }
}

extern "C" void kernel_launch(void* const* d_in, const int* in_sizes, int n_in,
                              void* d_out, int out_size, void* d_ws, size_t ws_size,
                              hipStream_t stream) {
  const float* obs   = (const float*)d_in[0];
  const float* trans = (const float*)d_in[1];
  const int*   tgt   = (const int*)d_in[2];
  float* out = (float*)d_out;

  hipMemsetAsync(out, 0, sizeof(float), stream);
  crf_fused<<<2 * NB, 256, 0, stream>>>(obs, trans, tgt, out);
}